// Round 1
// 224.089 us; speedup vs baseline: 1.0054x; 1.0054x over previous
//
#include <hip/hip_runtime.h>
#include <hip/hip_bf16.h>
#include <stdint.h>
#include <string.h>

// Problem constants (fixed by the reference)
#define N_ROWS 32768
#define DIM    512
#define CB     16   // codebooks
#define KW     16   // codewords per codebook
#define SV     32   // subvector length
#define MCOLS  1024

typedef __attribute__((ext_vector_type(8))) short bf16x8_t;  // 8 bf16 (4 VGPRs)
typedef __attribute__((ext_vector_type(4))) float f32x4_t;   // MFMA acc

// ws layout:
//   [0, 8)            f64 sum of X
//   [256, 256+64Ki)   f64 protos  [C][K][S]  (8192 doubles)
//   [66048, +2Ki)     f64 norms   [C][K]     (256 doubles)
//   [68352, +512Ki)   uint8 codes [N][C]

// ---------------------------------------------------------------------------
// Kernel 0: protos f32 -> f64 (coalesced) + codeword norms. One block.
// ---------------------------------------------------------------------------
__global__ __launch_bounds__(256) void prep_kernel(
    const float* __restrict__ protos, double* __restrict__ protos_d,
    double* __restrict__ norms_d)
{
    const int tid = threadIdx.x;
    #pragma unroll
    for (int j = 0; j < 32; ++j) {
        const int idx = j * 256 + tid;           // fully coalesced both sides
        protos_d[idx] = (double)protos[idx];
    }
    const float* src = protos + tid * SV;        // tid = ck
    double nk = 0.0;
    #pragma unroll
    for (int j = 0; j < SV; ++j) { double v = (double)src[j]; nk += v * v; }
    norms_d[tid] = nk;
}

// ---------------------------------------------------------------------------
// Kernel 1: PQ encode (argmin in f64, matches np ref) + sum(X).
// c = blockIdx.x & 15 -> SGPR by construction -> proto loads are s_load.
// NEW vs prev round: X subtile staged via LDS with fully-coalesced float4
// loads (old path: lane-stride-2048B gather -> L1 thrash at >4 waves/SIMD).
// XOR chunk swizzle keeps both LDS write and per-row ds_read_b128 at the
// 8-phase bank minimum.
// ---------------------------------------------------------------------------
__global__ __launch_bounds__(256, 4) void encode_kernel(
    const float* __restrict__ X, const double* __restrict__ protos_d,
    const double* __restrict__ norms_d, uint8_t* __restrict__ codes,
    double* __restrict__ sum_out)
{
    __shared__ __align__(16) float xs[256 * 32];   // 32 KiB swizzled subtile
    __shared__ double redsum[4];

    const int tid  = threadIdx.x;
    const int lane = tid & 63;
    const int wv   = tid >> 6;
    const int c    = blockIdx.x & 15;                 // wave-uniform (SGPR)
    const int n0   = (blockIdx.x >> 4) * 256;

    // --- stage 256 rows x 32 f32 (this codebook's subvectors), coalesced ---
    double sx = 0.0;
    {
        const int ch = tid & 7;          // 16B chunk within a row (0..7)
        const int rr = tid >> 3;         // 32 rows per iteration
        #pragma unroll
        for (int it = 0; it < 8; ++it) {
            const int row = it * 32 + rr;
            const float4 v = *(const float4*)(X + (size_t)(n0 + row) * DIM
                                              + c * SV + ch * 4);
            // chunk swizzle: stored chunk = ch ^ (row&7)
            *(float4*)&xs[row * 32 + ((ch ^ (row & 7)) << 2)] = v;
            sx += (double)v.x + (double)v.y + (double)v.z + (double)v.w;
        }
    }
    __syncthreads();

    // --- per-thread row: load subvector from LDS, convert to f64 once ---
    double xd[SV];
    #pragma unroll
    for (int j = 0; j < 8; ++j) {
        const float4 v = *(const float4*)&xs[tid * 32 + ((j ^ (tid & 7)) << 2)];
        xd[j * 4 + 0] = (double)v.x; xd[j * 4 + 1] = (double)v.y;
        xd[j * 4 + 2] = (double)v.z; xd[j * 4 + 3] = (double)v.w;
    }

    const double* __restrict__ Pd = protos_d + (size_t)c * (KW * SV);
    const double* __restrict__ Nd = norms_d + (size_t)c * KW;

    // argmin_k ( ||p_k||^2 - 2 x.p_k ), first-min wins (matches np.argmin).
    double best = 1e300;
    int bk = 0;
    #pragma unroll
    for (int k = 0; k < KW; ++k) {
        const double* pk = Pd + k * SV;
        double d0 = 0.0, d1 = 0.0, d2 = 0.0, d3 = 0.0;
        #pragma unroll
        for (int s = 0; s < 8; ++s) {
            d0 += xd[4 * s + 0] * pk[4 * s + 0];
            d1 += xd[4 * s + 1] * pk[4 * s + 1];
            d2 += xd[4 * s + 2] * pk[4 * s + 2];
            d3 += xd[4 * s + 3] * pk[4 * s + 3];
        }
        double dist = Nd[k] - 2.0 * ((d0 + d1) + (d2 + d3));
        if (dist < best) { best = dist; bk = k; }
    }
    codes[(size_t)(n0 + tid) * CB + c] = (uint8_t)bk;

    // Block-reduce sx -> one f64 atomic per block (for mean(X))
    #pragma unroll
    for (int off = 32; off > 0; off >>= 1) sx += __shfl_down(sx, off);
    if (lane == 0) redsum[wv] = sx;
    __syncthreads();
    if (tid == 0) {
        double s = redsum[0] + redsum[1] + redsum[2] + redsum[3];
        atomicAdd(sum_out, s);
    }
}

// ---------------------------------------------------------------------------
// Kernel 2: LUT gather-accumulate as an MFMA GEMM:
//   out[N,1024] = onehot(codes)[N,256] x (luts * mean)[256,1024]   (bf16 MFMA)
// Block tile: 64 cols x 512 rows; 4 waves, each wave 128 rows.
// NEW vs prev round:
//  - A one-hot fragments built in VALU (11 ops) instead of a data-dependent
//    ds_read_b128 from a 512-B LDS table (random-address bank conflicts +
//    lgkmcnt chain before every MFMA quad). Kills 64 conflicted LDS gathers
//    per wave and the associated latency chain.
//  - lut_s unpadded 32 KiB with XOR swizzle (k-chunk ^= (m&7)), bank-minimal
//    for both staging writes and b128 fragment reads.
//  - codes read directly from global (L2-hot: 16 sibling col-tile blocks
//    share each 8 KiB codes tile) -> no codes_s, no tbl: LDS = 32 KiB exactly
//    -> 4 blocks/CU (was 3).
// ---------------------------------------------------------------------------
__global__ __launch_bounds__(256, 4) void lut_mfma_kernel(
    const float* __restrict__ luts, const uint8_t* __restrict__ codes,
    const double* __restrict__ sum_in, float* __restrict__ out)
{
    __shared__ __align__(16) uint16_t lut_s[64 * 256];  // 32 KiB [m][k^swz] bf16

    const int tid   = threadIdx.x;
    const int mtile = blockIdx.x & 15;   // 16 col tiles of 64
    const int nblk  = blockIdx.x >> 4;   // 64 row blocks of 512
    const int m0 = mtile * 64;
    const int n0 = nblk * 512;

    const float scale = (float)(sum_in[0] * (1.0 / ((double)N_ROWS * (double)DIM)));

    // --- stage B slab: (luts * scale) -> bf16, transposed [m][k], swizzled ---
    for (int i = tid; i < 256 * 64; i += 256) {
        const int ck = i >> 6, m = i & 63;       // wave reads 1 ck-row, coalesced
        float v = luts[(size_t)ck * MCOLS + m0 + m] * scale;
        __hip_bfloat16 b = __float2bfloat16(v);
        lut_s[m * 256 + (ck ^ ((m & 7) << 3))] = *(const uint16_t*)&b;
    }
    __syncthreads();

    const int wv   = tid >> 6;
    const int lane = tid & 63;
    const int mloc = lane & 15;          // col-in-tile (A row / C col)
    const int half = lane >> 4;          // 0..3 (k half-group / C row quad)
    const int sel  = half & 1;
    const int h2   = half >> 1;
    const int shiftbase = h2 * 8;        // byte shift within code dword
    const int sel8 = sel * 8;
    const int swz  = (mloc & 7) << 3;    // u16-index XOR for B reads

    #pragma unroll
    for (int rtq = 0; rtq < 2; ++rtq) {  // two quads of row-tiles per wave
        const int rowbase = wv * 128 + rtq * 64;   // within block

        // this lane's code dwords for its 4 row-tiles, straight from global
        uint4 crow[4];
        #pragma unroll
        for (int rt = 0; rt < 4; ++rt)
            crow[rt] = *(const uint4*)(codes
                         + (size_t)(n0 + rowbase + rt * 16 + mloc) * CB);

        f32x4_t acc[4][4];               // [rt][ct] : 64 regs
        #pragma unroll
        for (int rt = 0; rt < 4; ++rt)
            #pragma unroll
            for (int ct = 0; ct < 4; ++ct)
                acc[rt][ct] = (f32x4_t){0.f, 0.f, 0.f, 0.f};

        #pragma unroll
        for (int ki = 0; ki < 8; ++ki) { // k = ki*32 .. +32 (2 codebooks)
            // B fragments for the 4 col-subtiles (reused across 4 row-tiles)
            bf16x8_t bf[4];
            const int kidx = (ki * 32 + half * 8) ^ swz;
            #pragma unroll
            for (int ct = 0; ct < 4; ++ct) {
                const uint16_t* bp = lut_s + (ct * 16 + mloc) * 256 + kidx;
                bf[ct] = *reinterpret_cast<const bf16x8_t*>(bp);
            }
            #pragma unroll
            for (int rt = 0; rt < 4; ++rt) {
                const uint32_t cws[4] = {crow[rt].x, crow[rt].y,
                                         crow[rt].z, crow[rt].w};
                const uint32_t code =
                    (cws[ki >> 1] >> (shiftbase + (ki & 1) * 16)) & 0xffu;
                // one-hot A fragment in VALU: slot t = code - sel*8 (if 0..7)
                const int t = (int)code - sel8;           // -8..15
                const uint64_t sh = 0x3F80ull << ((t & 3) * 16);
                const int q = t >> 2;                     // 0 -> lo, 1 -> hi
                union { uint64_t u[2]; bf16x8_t v8; } A;
                A.u[0] = (q == 0) ? sh : 0ull;
                A.u[1] = (q == 1) ? sh : 0ull;
                #pragma unroll
                for (int ct = 0; ct < 4; ++ct)
                    acc[rt][ct] = __builtin_amdgcn_mfma_f32_16x16x32_bf16(
                        A.v8, bf[ct], acc[rt][ct], 0, 0, 0);
            }
        }

        // epilogue: C layout col=lane&15, row=half*4+reg  [m89-verified]
        #pragma unroll
        for (int rt = 0; rt < 4; ++rt) {
            const int grow = n0 + rowbase + rt * 16 + half * 4;
            #pragma unroll
            for (int reg = 0; reg < 4; ++reg) {
                float* op = out + (size_t)(grow + reg) * MCOLS + m0 + mloc;
                #pragma unroll
                for (int ct = 0; ct < 4; ++ct)
                    op[ct * 16] = acc[rt][ct][reg];
            }
        }
    }
}

// ---------------------------------------------------------------------------
extern "C" void kernel_launch(void* const* d_in, const int* in_sizes, int n_in,
                              void* d_out, int out_size, void* d_ws, size_t ws_size,
                              hipStream_t stream) {
    const float* X      = (const float*)d_in[0];   // [N, D]
    const float* protos = (const float*)d_in[1];   // [C, K, S]
    const float* luts   = (const float*)d_in[2];   // [C, K, M]
    float* out = (float*)d_out;                    // [N, M] f32

    double*  sum_ws   = (double*)d_ws;
    double*  protos_d = (double*)((uint8_t*)d_ws + 256);
    double*  norms_d  = (double*)((uint8_t*)d_ws + 66048);
    uint8_t* codes    = (uint8_t*)d_ws + 68352;    // N*CB = 512 KiB, 16B-aligned

    // ws is re-poisoned to 0xAA before every launch: zero the f64 accumulator.
    hipMemsetAsync(d_ws, 0, 8, stream);

    prep_kernel<<<dim3(1), dim3(256), 0, stream>>>(protos, protos_d, norms_d);

    // 128 rowsupers x 16 codebooks; one block = 256 rows of one codebook.
    encode_kernel<<<dim3(2048), dim3(256), 0, stream>>>(X, protos_d, norms_d,
                                                        codes, sum_ws);

    // 16 col tiles x 64 row blocks of 512 rows.
    lut_mfma_kernel<<<dim3(1024), dim3(256), 0, stream>>>(luts, codes, sum_ws, out);
}